// Round 17
// baseline (419.975 us; speedup 1.0000x reference)
//
#include <hip/hip_runtime.h>
#include <hip/hip_bf16.h>

#define B_   4
#define L_   2048
#define D_   1024
#define H_   16
#define DH_  64
#define DFF_ 4096
#define M_   (B_ * L_)   // 8192

typedef __attribute__((ext_vector_type(8))) short bf16x8;
typedef __attribute__((ext_vector_type(4))) float f32x4;

#define GLOAD16(gp, lp)                                                       \
  __builtin_amdgcn_global_load_lds(                                           \
      (const __attribute__((address_space(1))) unsigned int*)(gp),            \
      (__attribute__((address_space(3))) unsigned int*)(lp), 16, 0, 0)

#if __has_builtin(__builtin_amdgcn_exp2f)
#define EXP2F(x) __builtin_amdgcn_exp2f(x)
#else
#define EXP2F(x) exp2f(x)
#endif

__device__ __forceinline__ float bf2f(unsigned short u) {
  return __uint_as_float(((unsigned)u) << 16);
}

// ---- fused prep + weight transpose, single launch (20512 blocks) ---------
__global__ void prep_and_transpose(
    const float4* __restrict__ x4, ushort4* __restrict__ xb4,
    const unsigned int* __restrict__ mraw, float* __restrict__ maskf,
    const float* __restrict__ bq, const float* __restrict__ bk,
    const float* __restrict__ bv, float* __restrict__ biasc,
    const float* __restrict__ wq, const float* __restrict__ wk,
    const float* __restrict__ wv, const float* __restrict__ wo,
    const float* __restrict__ w1, const float* __restrict__ w2,
    __hip_bfloat16* __restrict__ WQT, __hip_bfloat16* __restrict__ WKT,
    __hip_bfloat16* __restrict__ WVT, __hip_bfloat16* __restrict__ WOT,
    __hip_bfloat16* __restrict__ W1T, __hip_bfloat16* __restrict__ W2T) {
  const int id = blockIdx.x;
  if (id < 8192) {
    const int i = id * 256 + threadIdx.x;
    float4 v = x4[i];
    __hip_bfloat16 a = __float2bfloat16(v.x);
    __hip_bfloat16 b = __float2bfloat16(v.y);
    __hip_bfloat16 c = __float2bfloat16(v.z);
    __hip_bfloat16 d = __float2bfloat16(v.w);
    ushort4 o;
    o.x = *reinterpret_cast<unsigned short*>(&a);
    o.y = *reinterpret_cast<unsigned short*>(&b);
    o.z = *reinterpret_cast<unsigned short*>(&c);
    o.w = *reinterpret_cast<unsigned short*>(&d);
    xb4[i] = o;
    return;
  }
  if (id < 8224) {
    __shared__ int flags[2];
    if (threadIdx.x < 2) flags[threadIdx.x] = 0;
    __syncthreads();
    int nf32 = 0, n01 = 0;
    for (int i = threadIdx.x; i < 2048; i += 256) {
      unsigned w = mraw[i];
      if (w != 0u && w != 0x3f800000u) nf32 = 1;
      if (w > 1u) n01 = 1;
    }
    if (nf32) atomicOr(&flags[0], 1);
    if (n01)  atomicOr(&flags[1], 1);
    __syncthreads();
    const int mode = (!flags[0]) ? 0 : ((!flags[1]) ? 1 : 2);  // f32/i32/u8
    const int mi = (id - 8192) * 256 + threadIdx.x;
    if (mi < B_ * L_) {
      bool mk;
      if (mode == 0)      mk = reinterpret_cast<const float*>(mraw)[mi] != 0.f;
      else if (mode == 1) mk = reinterpret_cast<const int*>(mraw)[mi] != 0;
      else                mk = reinterpret_cast<const unsigned char*>(mraw)[mi] != 0;
      // fixed-max softmax: keep -> -32 (fixed max folded), masked -> -1e12
      maskf[mi] = mk ? -1e12f : -32.0f;
    }
    if (id == 8192) {
#pragma unroll
      for (int j = 0; j < 4; ++j) {
        const int c = j * 256 + threadIdx.x;
        biasc[c] = bq[c];
        biasc[D_ + c] = bk[c];
        biasc[2 * D_ + c] = bv[c];
      }
    }
    return;
  }
  // ---- weight transpose tiles ----
  __shared__ float t[32][33];
  const int wid = id - 8224;
  const float* W;
  __hip_bfloat16* Wt;
  int K, N, rem;
  if (wid < 4096) {
    const int which = wid >> 10;
    W  = which == 0 ? wq : which == 1 ? wk : which == 2 ? wv : wo;
    Wt = which == 0 ? WQT : which == 1 ? WKT : which == 2 ? WVT : WOT;
    K = D_; N = D_; rem = wid & 1023;
  } else if (wid < 8192) {
    W = w1; Wt = W1T; K = D_; N = DFF_; rem = wid - 4096;
  } else {
    W = w2; Wt = W2T; K = DFF_; N = D_; rem = wid - 8192;
  }
  const int ntx = N >> 5;
  const int n0 = (rem % ntx) * 32, k0 = (rem / ntx) * 32;
  const int tx = threadIdx.x & 31, ty = threadIdx.x >> 5;  // 32x8 flattened
#pragma unroll
  for (int i = 0; i < 4; ++i)
    t[ty + i * 8][tx] = W[(size_t)(k0 + ty + i * 8) * N + n0 + tx];
  __syncthreads();
#pragma unroll
  for (int i = 0; i < 4; ++i)
    Wt[(size_t)(n0 + ty + i * 8) * K + k0 + tx] =
        __float2bfloat16(t[tx][ty + i * 8]);
}

// ---------------- V[b*L+l][D] bf16 -> VT[(b*D+d)][L] bf16 ----------------
__global__ void transpose_v(const __hip_bfloat16* __restrict__ Vin,
                            __hip_bfloat16* __restrict__ Vt) {
  __shared__ __hip_bfloat16 t[32][33];
  const int l0 = blockIdx.x * 32, d0 = blockIdx.y * 32, b = blockIdx.z;
  const int tx = threadIdx.x, ty = threadIdx.y;
#pragma unroll
  for (int i = 0; i < 4; ++i)
    t[ty + i * 8][tx] = Vin[(size_t)(b * L_ + l0 + ty + i * 8) * D_ + d0 + tx];
  __syncthreads();
#pragma unroll
  for (int i = 0; i < 4; ++i) {
    int d = d0 + ty + i * 8;
    Vt[(size_t)(b * D_ + d) * L_ + l0 + tx] = t[tx][ty + i * 8];
  }
}

// =================== 256x256 8-phase GEMM (T2+T3+T4+T5) ===================
#define STAGE8(matptr, stride, ldsbase, tile, kh, rowbase)                    \
  {                                                                           \
    _Pragma("unroll")                                                         \
    for (int j_ = 0; j_ < 2; ++j_) {                                          \
      const int s_ = j_ * 512 + tid;                                          \
      const int row_ = s_ >> 2;                                               \
      const int q_ = (s_ & 3) ^ ((row_ >> 1) & 3);                            \
      GLOAD16(&matptr[(size_t)((rowbase) + row_) * (stride) + (tile) * 64 +   \
                      (kh) * 32 + q_ * 8],                                    \
              (ldsbase) + (j_ * 512 + (w << 6)) * 16);                        \
    }                                                                         \
  }

#define PHASE8(bufoff, rh, ks, dovm, ...)                                     \
  {                                                                           \
    if ((rh) == 0) {                                                          \
      _Pragma("unroll")                                                       \
      for (int j = 0; j < 4; ++j) {                                           \
        const int br = wn * 64 + j * 16 + r16;                                \
        bfr[j] = *reinterpret_cast<const bf16x8*>(                            \
            ldsB + (bufoff) + (ks) * 16384 + br * 64 +                        \
            ((hi * 16) ^ (((br >> 1) & 3) << 4)));                            \
      }                                                                       \
    }                                                                         \
    bf16x8 af[4];                                                             \
    _Pragma("unroll")                                                         \
    for (int i = 0; i < 4; ++i) {                                             \
      const int ar = wm * 128 + (rh) * 64 + i * 16 + r16;                     \
      af[i] = *reinterpret_cast<const bf16x8*>(                               \
          ldsA + (bufoff) + (ks) * 16384 + ar * 64 +                          \
          ((hi * 16) ^ (((ar >> 1) & 3) << 4)));                              \
    }                                                                         \
    __VA_ARGS__;                                                              \
    __builtin_amdgcn_s_barrier();                                             \
    asm volatile("s_waitcnt lgkmcnt(0)" ::: "memory");                        \
    __builtin_amdgcn_sched_barrier(0);                                        \
    __builtin_amdgcn_s_setprio(1);                                            \
    _Pragma("unroll")                                                         \
    for (int i = 0; i < 4; ++i)                                               \
      _Pragma("unroll")                                                       \
      for (int j = 0; j < 4; ++j)                                             \
        acc[(rh) * 4 + i][j] = __builtin_amdgcn_mfma_f32_16x16x32_bf16(       \
            af[i], bfr[j], acc[(rh) * 4 + i][j], 0, 0, 0);                    \
    __builtin_amdgcn_s_setprio(0);                                            \
    if (dovm) {                                                               \
      asm volatile("s_waitcnt vmcnt(4)" ::: "memory");                        \
      __builtin_amdgcn_sched_barrier(0);                                      \
    }                                                                         \
    __builtin_amdgcn_s_barrier();                                             \
  }

template <int EP>
__global__ __launch_bounds__(512, 1) void gemm8(
    const __hip_bfloat16* __restrict__ A, const __hip_bfloat16* __restrict__ Bt,
    const float* __restrict__ bias, void* __restrict__ out,
    int M, int N, int K, int lda, int ldb) {
  __shared__ __align__(16) char lds8[131072];
  char* const ldsA = lds8;
  char* const ldsB = lds8 + 65536;

  const int tid = threadIdx.x;
  const int lane = tid & 63;
  const int w = tid >> 6;           // 0..7
  const int wm = w >> 2;            // 0..1
  const int wn = w & 3;             // 0..3
  const int r16 = lane & 15;
  const int hi = lane >> 4;

  const int nwg = gridDim.x;
  const int orig = blockIdx.x;
  const int swz = (orig & 7) * (nwg >> 3) + (orig >> 3);

  int bm, bn, kh = 0;
  const __hip_bfloat16* Ap = A;
  const __hip_bfloat16* Bp = Bt;
  if (EP == 4) {
    kh = swz & 1;
    const int rest = swz >> 1;
    bm = (rest & 31) * 256;
    bn = (rest >> 5) * 256;
    Ap += (size_t)kh * K;
    Bp += (size_t)kh * K;
  } else {
    bm = (swz & 31) * 256;          // M/256 == 32 always here
    bn = (swz >> 5) * 256;
  }

  f32x4 acc[8][4];
#pragma unroll
  for (int i = 0; i < 8; ++i)
#pragma unroll
    for (int j = 0; j < 4; ++j) acc[i][j] = (f32x4){0.f, 0.f, 0.f, 0.f};
  bf16x8 bfr[4];

  const int nkt = K >> 6;           // K-tiles of 64
  const int nit = nkt >> 1;         // iterations (2 K-tiles each)

  // prologue: t0 {kh0,kh1}, t1 {kh0}
  STAGE8(Ap, lda, ldsA, 0, 0, bm);
  STAGE8(Bp, ldb, ldsB, 0, 0, bn);
  STAGE8(Ap, lda, ldsA + 16384, 0, 1, bm);
  STAGE8(Bp, ldb, ldsB + 16384, 0, 1, bn);
  STAGE8(Ap, lda, ldsA + 32768, 1, 0, bm);
  STAGE8(Bp, ldb, ldsB + 32768, 1, 0, bn);
  asm volatile("s_waitcnt vmcnt(4)" ::: "memory");
  __builtin_amdgcn_sched_barrier(0);
  __builtin_amdgcn_s_barrier();

  for (int it = 0; it < nit; ++it) {
    const int kt = it * 2;
    const bool hn = (it + 1) < nit;
    // tile kt from buf0
    PHASE8(0, 0, 0, 0, STAGE8(Ap, lda, ldsA + 49152, kt + 1, 1, bm));
    PHASE8(0, 1, 0, 0, STAGE8(Bp, ldb, ldsB + 49152, kt + 1, 1, bn));
    PHASE8(0, 0, 1, 0, if (hn) STAGE8(Ap, lda, ldsA, kt + 2, 0, bm));
    PHASE8(0, 1, 1, 1, if (hn) STAGE8(Bp, ldb, ldsB, kt + 2, 0, bn));
    // tile kt+1 from buf1
    PHASE8(32768, 0, 0, 0, if (hn) STAGE8(Ap, lda, ldsA + 16384, kt + 2, 1, bm));
    PHASE8(32768, 1, 0, 0, if (hn) STAGE8(Bp, ldb, ldsB + 16384, kt + 2, 1, bn));
    PHASE8(32768, 0, 1, 0, if (hn) STAGE8(Ap, lda, ldsA + 32768, kt + 3, 0, bm));
    PHASE8(32768, 1, 1, 1, if (hn) STAGE8(Bp, ldb, ldsB + 32768, kt + 3, 0, bn));
  }

  // epilogue
#pragma unroll
  for (int ri = 0; ri < 8; ++ri) {
#pragma unroll
    for (int j = 0; j < 4; ++j) {
      const int col = bn + wn * 64 + j * 16 + r16;
      const float bv = (EP == 4) ? 0.f : bias[col];
#pragma unroll
      for (int r = 0; r < 4; ++r) {
        const int row = bm + wm * 128 + ri * 16 + hi * 4 + r;
        const float v = acc[ri][j][r] + bv;
        if (EP == 1) {
          ((__hip_bfloat16*)out)[(size_t)row * N + col] =
              __float2bfloat16(v > 0.f ? v : 0.f);
        } else if (EP == 3) {  // QKV routing
          __hip_bfloat16* outp =
              (__hip_bfloat16*)out + (size_t)(col >> 10) * (M_ * D_);
          outp[(size_t)row * 1024 + (col & 1023)] = __float2bfloat16(v);
        } else {  // EP == 4: split-K partial, bf16
          __hip_bfloat16* outp =
              (__hip_bfloat16*)out + (size_t)kh * ((size_t)M * N);
          outp[(size_t)row * N + col] = __float2bfloat16(v);
        }
      }
    }
  }
}

// ---------------- GEMM 128x128 2-phase (fallback path only) ---------------
template <int EP>
__global__ __launch_bounds__(256) void gemm_bt(
    const __hip_bfloat16* __restrict__ A, const __hip_bfloat16* __restrict__ Bt,
    const float* __restrict__ bias, const float* __restrict__ res,
    void* __restrict__ out, int M, int N, int K) {
  __shared__ __align__(16) char As[128 * 64];
  __shared__ __align__(16) char Bs[128 * 64];
  const int tid = threadIdx.x;
  const int lane = tid & 63;
  const int w = tid >> 6;
  const int wm = w >> 1, wn = w & 1;
  const int bm = blockIdx.x * 128;
  const int bn = blockIdx.y * 128;
  const int r16 = lane & 15;
  const int hi = lane >> 4;

  f32x4 acc[4][4];
#pragma unroll
  for (int m = 0; m < 4; ++m)
#pragma unroll
    for (int n = 0; n < 4; ++n) acc[m][n] = (f32x4){0.f, 0.f, 0.f, 0.f};

  for (int k0 = 0; k0 < K; k0 += 32) {
    __syncthreads();
#pragma unroll
    for (int c = 0; c < 2; ++c) {
      const int seg = c * 256 + tid;
      const int row = seg >> 2;
      const int csl = (seg & 3) ^ (row & 3);
      GLOAD16(&A[(size_t)(bm + row) * K + k0 + csl * 8],
              As + (c * 256 + w * 64) * 16);
      GLOAD16(&Bt[(size_t)(bn + row) * K + k0 + csl * 8],
              Bs + (c * 256 + w * 64) * 16);
    }
    __syncthreads();

    bf16x8 af[4], bfr[4];
#pragma unroll
    for (int m = 0; m < 4; ++m) {
      const int arow = wm * 64 + m * 16 + r16;
      af[m] = *reinterpret_cast<const bf16x8*>(
          As + arow * 64 + ((hi * 16) ^ ((arow & 3) << 4)));
    }
#pragma unroll
    for (int n = 0; n < 4; ++n) {
      const int brow = wn * 64 + n * 16 + r16;
      bfr[n] = *reinterpret_cast<const bf16x8*>(
          Bs + brow * 64 + ((hi * 16) ^ ((brow & 3) << 4)));
    }
#pragma unroll
    for (int m = 0; m < 4; ++m)
#pragma unroll
      for (int n = 0; n < 4; ++n)
        acc[m][n] = __builtin_amdgcn_mfma_f32_16x16x32_bf16(af[m], bfr[n],
                                                            acc[m][n], 0, 0, 0);
  }

  const int rg = hi * 4;
#pragma unroll
  for (int m = 0; m < 4; ++m) {
#pragma unroll
    for (int n = 0; n < 4; ++n) {
      const int col = bn + wn * 64 + n * 16 + r16;
      const float bv = bias[col];
#pragma unroll
      for (int r = 0; r < 4; ++r) {
        const int row = bm + wm * 64 + m * 16 + rg + r;
        const size_t idx = (size_t)row * N + col;
        float v = acc[m][n][r] + bv;
        if (EP == 0) {
          ((__hip_bfloat16*)out)[idx] = __float2bfloat16(v);
        } else {
          ((float*)out)[idx] = v + res[idx];
        }
      }
    }
  }
}

// ----- flash attention: 8-wave blocks, shared K/V staging -----------------
// grid 512 blocks (XCD-remapped); block 512 = 8 waves; wave owns 32 q rows;
// block covers 256 q rows. K/V tile staged once serves all 8 waves (2x less
// staging per q-row than 4-wave). LDS 48.25 KB -> 3 blocks/CU = 24 waves/CU.
__global__ __launch_bounds__(512) void attn_kernel(
    const __hip_bfloat16* __restrict__ Qg, const __hip_bfloat16* __restrict__ Kg,
    const __hip_bfloat16* __restrict__ VTg,  // [(b*D + h*64+dh)][L]
    const float* __restrict__ maskf,         // [B*L]: -32 keep / -1e12 masked
    __hip_bfloat16* __restrict__ Og) {
  __shared__ __align__(16) char Kl[64 * 128];        // [kv][d], swizzled (8KB)
  __shared__ __align__(16) char Vl[64 * 128];        // [dh][kv], swizzled (8KB)
  __shared__ __align__(16) char Pl[8][32 * 128];     // per-wave [q][k] (32KB)
  __shared__ float maskb[64];

  const int tid = threadIdx.x;
  const int lane = tid & 63;
  const int w = tid >> 6;               // 0..7
  const int hi = lane >> 4;
  const int r16 = lane & 15;
  const int swzk = (r16 & 7) << 4;

  const int nwg = gridDim.x;            // 512
  const int orig = blockIdx.x;
  const int swb = (orig & 7) * (nwg >> 3) + (orig >> 3);
  const int qb = swb & 7;               // 8 q-blocks of 256
  const int bh = swb >> 3;
  const int b = bh >> 4;
  const int h = bh & 15;
  const int qbase = qb * 256 + w * 32;

  const float C = 0.18033688011112042f;  // 0.125 * log2(e)
  const short ob = (short)0x3f80;        // bf16 1.0
  const bf16x8 vone = {ob, ob, ob, ob, ob, ob, ob, ob};

  bf16x8 qf[2][2];
#pragma unroll
  for (int m = 0; m < 2; ++m)
#pragma unroll
    for (int ks = 0; ks < 2; ++ks)
      qf[m][ks] = *reinterpret_cast<const bf16x8*>(
          &Qg[(size_t)(b * L_ + qbase + m * 16 + r16) * D_ + h * DH_ +
              ks * 32 + hi * 8]);

  f32x4 o[2][4];
  f32x4 oden[2];
#pragma unroll
  for (int m = 0; m < 2; ++m) {
    oden[m] = (f32x4){0.f, 0.f, 0.f, 0.f};
#pragma unroll
    for (int nd = 0; nd < 4; ++nd) o[m][nd] = (f32x4){0.f, 0.f, 0.f, 0.f};
  }

  char* const Plw = Pl[w];

  for (int kv0 = 0; kv0 < L_; kv0 += 64) {
    __syncthreads();
    // 512 threads: 1 K-load + 1 V-load each (16B) stages the full 8KB+8KB
    {
      const int row = tid >> 3;                 // 0..63
      const int csl = (tid & 7) ^ (row & 7);
      GLOAD16(&Kg[(size_t)(b * L_ + kv0 + row) * D_ + h * DH_ + csl * 8],
              Kl + (w * 64) * 16);
      GLOAD16(&VTg[(size_t)(b * D_ + h * DH_ + row) * L_ + kv0 + csl * 8],
              Vl + (w * 64) * 16);
    }
    if (tid < 64) maskb[tid] = maskf[(size_t)b * L_ + kv0 + tid];
    __syncthreads();

    // S^T tiles: lane q = m*16+r16, k = n*16+hi*4+r
    f32x4 sacc[2][4];
#pragma unroll
    for (int m = 0; m < 2; ++m)
#pragma unroll
      for (int n = 0; n < 4; ++n) sacc[m][n] = (f32x4){0.f, 0.f, 0.f, 0.f};
    __builtin_amdgcn_s_setprio(1);
#pragma unroll
    for (int n = 0; n < 4; ++n) {
      const int krow = n * 16 + r16;
#pragma unroll
      for (int ks = 0; ks < 2; ++ks) {
        const bf16x8 kf = *reinterpret_cast<const bf16x8*>(
            Kl + krow * 128 + ((ks * 64 + hi * 16) ^ swzk));
#pragma unroll
        for (int m = 0; m < 2; ++m)
          sacc[m][n] = __builtin_amdgcn_mfma_f32_16x16x32_bf16(
              kf, qf[m][ks], sacc[m][n], 0, 0, 0);
      }
    }
    __builtin_amdgcn_s_setprio(0);

    // fixed-max softmax: e = 2^(S*C + mask); no max tracking, no sum chain.
    float4 mv[4];
#pragma unroll
    for (int n = 0; n < 4; ++n)
      mv[n] = *reinterpret_cast<const float4*>(&maskb[n * 16 + hi * 4]);
#pragma unroll
    for (int m = 0; m < 2; ++m) {
      const int prow = m * 16 + r16;
#pragma unroll
      for (int n = 0; n < 4; ++n) {
        const float e0 = EXP2F(fmaf(sacc[m][n][0], C, mv[n].x));
        const float e1 = EXP2F(fmaf(sacc[m][n][1], C, mv[n].y));
        const float e2 = EXP2F(fmaf(sacc[m][n][2], C, mv[n].z));
        const float e3 = EXP2F(fmaf(sacc[m][n][3], C, mv[n].w));
        union { unsigned long long u; unsigned short us[4]; } pk;
        __hip_bfloat16 t0 = __float2bfloat16(e0);
        __hip_bfloat16 t1 = __float2bfloat16(e1);
        __hip_bfloat16 t2 = __float2bfloat16(e2);
        __hip_bfloat16 t3 = __float2bfloat16(e3);
        pk.us[0] = *reinterpret_cast<unsigned short*>(&t0);
        pk.us[1] = *reinterpret_cast<unsigned short*>(&t1);
        pk.us[2] = *reinterpret_cast<unsigned short*>(&t2);
        pk.us[3] = *reinterpret_cast<unsigned short*>(&t3);
        *reinterpret_cast<unsigned long long*>(
            Plw + prow * 128 + ((n * 32 + hi * 8) ^ swzk)) = pk.u;
      }
    }

    // O += P V ; oden += P * ones (denominator rides the matrix pipe)
    bf16x8 pa[2][2];
#pragma unroll
    for (int m = 0; m < 2; ++m)
#pragma unroll
      for (int ks = 0; ks < 2; ++ks)
        pa[m][ks] = *reinterpret_cast<const bf16x8*>(
            Plw + (m * 16 + r16) * 128 + ((ks * 64 + hi * 16) ^ swzk));
    __builtin_amdgcn_s_setprio(1);
#pragma unroll
    for (int m = 0; m < 2; ++m)
#pragma unroll
      for (int ks = 0; ks < 2; ++ks)
        oden[m] = __builtin_amdgcn_mfma_f32_16x16x32_bf16(pa[m][ks], vone,
                                                          oden[m], 0, 0, 0);
#pragma unroll
    for (int nd = 0; nd < 4; ++nd) {
      const int vrow = nd * 16 + r16;
#pragma unroll
      for (int ks = 0; ks < 2; ++ks) {
        const bf16x8 vb = *reinterpret_cast<const bf16x8*>(
            Vl + vrow * 128 + ((ks * 64 + hi * 16) ^ swzk));
#pragma unroll
        for (int m = 0; m < 2; ++m)
          o[m][nd] = __builtin_amdgcn_mfma_f32_16x16x32_bf16(pa[m][ks], vb,
                                                             o[m][nd], 0, 0, 0);
      }
    }
    __builtin_amdgcn_s_setprio(0);
  }

  // normalize + store: oden row-layout == o row-layout (row = hi*4+r)
#pragma unroll
  for (int m = 0; m < 2; ++m) {
#pragma unroll
    for (int r = 0; r < 4; ++r) {
      const float ir = 1.f / oden[m][r];
      const int q = qbase + m * 16 + hi * 4 + r;
#pragma unroll
      for (int nd = 0; nd < 4; ++nd)
        Og[(size_t)(b * L_ + q) * D_ + h * DH_ + nd * 16 + r16] =
            __float2bfloat16(o[m][nd][r] * ir);
    }
  }
}

// ---------------- LayerNorm (row=1024) plain (fallback path) --------------
__global__ __launch_bounds__(256) void layernorm_kernel(
    const float* __restrict__ in, const float* __restrict__ g,
    const float* __restrict__ be, float* __restrict__ outf,
    __hip_bfloat16* __restrict__ outb) {
  const int row = blockIdx.x;
  const int tid = threadIdx.x;
  const float4 v = reinterpret_cast<const float4*>(in + (size_t)row * D_)[tid];
  float s = v.x + v.y + v.z + v.w;
  float ss = v.x * v.x + v.y * v.y + v.z * v.z + v.w * v.w;
#pragma unroll
  for (int off = 1; off < 64; off <<= 1) {
    s += __shfl_xor(s, off, 64);
    ss += __shfl_xor(ss, off, 64);
  }
  __shared__ float red[8];
  const int w = tid >> 6, lane = tid & 63;
  if (lane == 0) { red[w] = s; red[4 + w] = ss; }
  __syncthreads();
  s = red[0] + red[1] + red[2] + red[3];
  ss = red[4] + red[5] + red[6] + red[7];
  const float mu = s * (1.f / D_);
  const float rs = rsqrtf(ss * (1.f / D_) - mu * mu + 1e-5f);
  const float4 gv = reinterpret_cast<const float4*>(g)[tid];
  const float4 bv = reinterpret_cast<const float4*>(be)[tid];
  float4 ov;
  ov.x = (v.x - mu) * rs * gv.x + bv.x;
  ov.y = (v.y - mu) * rs * gv.y + bv.y;
  ov.z = (v.z - mu) * rs * gv.z + bv.z;
  ov.w = (v.w - mu) * rs * gv.w + bv.w;
  reinterpret_cast<float4*>(outf + (size_t)row * D_)[tid] = ov;
  if (outb) {
    __hip_bfloat16 t[4] = {__float2bfloat16(ov.x), __float2bfloat16(ov.y),
                           __float2bfloat16(ov.z), __float2bfloat16(ov.w)};
    *reinterpret_cast<uint2*>(&outb[(size_t)row * D_ + tid * 4]) =
        *reinterpret_cast<const uint2*>(t);
  }
}

// -------- LN1 fused: v = OP(bf16) + x; LN -> R1(f32), XB(bf16) (fallback) --
__global__ __launch_bounds__(256) void ln_addres(
    const __hip_bfloat16* __restrict__ OP, const float* __restrict__ x,
    const float* __restrict__ g, const float* __restrict__ be,
    float* __restrict__ outf, __hip_bfloat16* __restrict__ outb) {
  const int row = blockIdx.x;
  const int tid = threadIdx.x;
  const ushort4 a4 = reinterpret_cast<const ushort4*>(OP + (size_t)row * D_)[tid];
  const float4 xr = reinterpret_cast<const float4*>(x + (size_t)row * D_)[tid];
  float4 v;
  v.x = bf2f(a4.x) + xr.x;
  v.y = bf2f(a4.y) + xr.y;
  v.z = bf2f(a4.z) + xr.z;
  v.w = bf2f(a4.w) + xr.w;
  float s = v.x + v.y + v.z + v.w;
  float ss = v.x * v.x + v.y * v.y + v.z * v.z + v.w * v.w;
#pragma unroll
  for (int off = 1; off < 64; off <<= 1) {
    s += __shfl_xor(s, off, 64);
    ss += __shfl_xor(ss, off, 64);
  }
  __shared__ float red[8];
  const int w = tid >> 6, lane = tid & 63;
  if (lane == 0) { red[w] = s; red[4 + w] = ss; }
  __syncthreads();
  s = red[0] + red[1] + red[2] + red[3];
  ss = red[4] + red[5] + red[6] + red[7];
  const float mu = s * (1.f / D_);
  const float rs = rsqrtf(ss * (1.f / D_) - mu * mu + 1e-5f);
  const float4 gv = reinterpret_cast<const float4*>(g)[tid];
  const float4 bv = reinterpret_cast<const float4*>(be)[tid];
  float4 ov;
  ov.x = (v.x - mu) * rs * gv.x + bv.x;
  ov.y = (v.y - mu) * rs * gv.y + bv.y;
  ov.z = (v.z - mu) * rs * gv.z + bv.z;
  ov.w = (v.w - mu) * rs * gv.w + bv.w;
  reinterpret_cast<float4*>(outf + (size_t)row * D_)[tid] = ov;
  __hip_bfloat16 t[4] = {__float2bfloat16(ov.x), __float2bfloat16(ov.y),
                         __float2bfloat16(ov.z), __float2bfloat16(ov.w)};
  *reinterpret_cast<uint2*>(&outb[(size_t)row * D_ + tid * 4]) =
      *reinterpret_cast<const uint2*>(t);
}

// -------- LN1 fused with O-proj split-K combine: v = P0+P1+x+bo; LN -------
// residual out in f32 (precision-critical for final LN2)
__global__ __launch_bounds__(256) void ln_addres_sk(
    const __hip_bfloat16* __restrict__ P0, const __hip_bfloat16* __restrict__ P1,
    const float* __restrict__ x, const float* __restrict__ bo,
    const float* __restrict__ g, const float* __restrict__ be,
    float* __restrict__ outf, __hip_bfloat16* __restrict__ outb) {
  const int row = blockIdx.x;
  const int tid = threadIdx.x;
  const ushort4 a4 = reinterpret_cast<const ushort4*>(P0 + (size_t)row * D_)[tid];
  const ushort4 b4 = reinterpret_cast<const ushort4*>(P1 + (size_t)row * D_)[tid];
  const float4 xr = reinterpret_cast<const float4*>(x + (size_t)row * D_)[tid];
  const float4 bb = reinterpret_cast<const float4*>(bo)[tid];
  float4 v;
  v.x = bf2f(a4.x) + bf2f(b4.x) + xr.x + bb.x;
  v.y = bf2f(a4.y) + bf2f(b4.y) + xr.y + bb.y;
  v.z = bf2f(a4.z) + bf2f(b4.z) + xr.z + bb.z;
  v.w = bf2f(a4.w) + bf2f(b4.w) + xr.w + bb.w;
  float s = v.x + v.y + v.z + v.w;
  float ss = v.x * v.x + v.y * v.y + v.z * v.z + v.w * v.w;
#pragma unroll
  for (int off = 1; off < 64; off <<= 1) {
    s += __shfl_xor(s, off, 64);
    ss += __shfl_xor(ss, off, 64);
  }
  __shared__ float red[8];
  const int w = tid >> 6, lane = tid & 63;
  if (lane == 0) { red[w] = s; red[4 + w] = ss; }
  __syncthreads();
  s = red[0] + red[1] + red[2] + red[3];
  ss = red[4] + red[5] + red[6] + red[7];
  const float mu = s * (1.f / D_);
  const float rs = rsqrtf(ss * (1.f / D_) - mu * mu + 1e-5f);
  const float4 gv = reinterpret_cast<const float4*>(g)[tid];
  const float4 bv = reinterpret_cast<const float4*>(be)[tid];
  float4 ov;
  ov.x = (v.x - mu) * rs * gv.x + bv.x;
  ov.y = (v.y - mu) * rs * gv.y + bv.y;
  ov.z = (v.z - mu) * rs * gv.z + bv.z;
  ov.w = (v.w - mu) * rs * gv.w + bv.w;
  reinterpret_cast<float4*>(outf + (size_t)row * D_)[tid] = ov;
  __hip_bfloat16 t[4] = {__float2bfloat16(ov.x), __float2bfloat16(ov.y),
                         __float2bfloat16(ov.z), __float2bfloat16(ov.w)};
  *reinterpret_cast<uint2*>(&outb[(size_t)row * D_ + tid * 4]) =
      *reinterpret_cast<const uint2*>(t);
}

// ------- combine bf16 split-K partials + f32 residual + bias + LN ---------
__global__ __launch_bounds__(256) void combine_ln2(
    const __hip_bfloat16* __restrict__ P0, const __hip_bfloat16* __restrict__ P1,
    const float* __restrict__ res, const float* __restrict__ b2,
    const float* __restrict__ g, const float* __restrict__ be,
    float* __restrict__ out) {
  const int row = blockIdx.x;
  const int tid = threadIdx.x;
  const ushort4 a4 =
      reinterpret_cast<const ushort4*>(P0 + (size_t)row * D_)[tid];
  const ushort4 b4 =
      reinterpret_cast<const ushort4*>(P1 + (size_t)row * D_)[tid];
  const float4 rr = reinterpret_cast<const float4*>(res + (size_t)row * D_)[tid];
  const float4 bb = reinterpret_cast<const float4*>(b2)[tid];
  float4 v;
  v.x = bf2f(a4.x) + bf2f(b4.x) + rr.x + bb.x;
  v.y = bf2f(a4.y) + bf2f(b4.y) + rr.y + bb.y;
  v.z = bf2f(a4.z) + bf2f(b4.z) + rr.z + bb.z;
  v.w = bf2f(a4.w) + bf2f(b4.w) + rr.w + bb.w;
  float s = v.x + v.y + v.z + v.w;
  float ss = v.x * v.x + v.y * v.y + v.z * v.z + v.w * v.w;
#pragma unroll
  for (int off = 1; off < 64; off <<= 1) {
    s += __shfl_xor(s, off, 64);
    ss += __shfl_xor(ss, off, 64);
  }
  __shared__ float red[8];
  const int w = tid >> 6, lane = tid & 63;
  if (lane == 0) { red[w] = s; red[4 + w] = ss; }
  __syncthreads();
  s = red[0] + red[1] + red[2] + red[3];
  ss = red[4] + red[5] + red[6] + red[7];
  const float mu = s * (1.f / D_);
  const float rs = rsqrtf(ss * (1.f / D_) - mu * mu + 1e-5f);
  const float4 gv = reinterpret_cast<const float4*>(g)[tid];
  const float4 bv = reinterpret_cast<const float4*>(be)[tid];
  float4 ov;
  ov.x = (v.x - mu) * rs * gv.x + bv.x;
  ov.y = (v.y - mu) * rs * gv.y + bv.y;
  ov.z = (v.z - mu) * rs * gv.z + bv.z;
  ov.w = (v.w - mu) * rs * gv.w + bv.w;
  reinterpret_cast<float4*>(out + (size_t)row * D_)[tid] = ov;
}

// ---------------- launch ----------------
extern "C" void kernel_launch(void* const* d_in, const int* in_sizes, int n_in,
                              void* d_out, int out_size, void* d_ws,
                              size_t ws_size, hipStream_t stream) {
  (void)in_sizes; (void)n_in; (void)out_size;
  const float* x   = (const float*)d_in[0];
  const void*  msk = d_in[1];
  const float* wq  = (const float*)d_in[2];
  const float* bq  = (const float*)d_in[3];
  const float* wk  = (const float*)d_in[4];
  const float* bk  = (const float*)d_in[5];
  const float* wv  = (const float*)d_in[6];
  const float* bv  = (const float*)d_in[7];
  const float* wo  = (const float*)d_in[8];
  const float* bo  = (const float*)d_in[9];
  const float* w1  = (const float*)d_in[10];
  const float* b1  = (const float*)d_in[11];
  const float* w2  = (const float*)d_in[12];
  const float* b2  = (const float*)d_in[13];
  const float* g1  = (const float*)d_in[14];
  const float* be1 = (const float*)d_in[15];
  const float* g2  = (const float*)d_in[16];
  const float* be2 = (const float*)d_in[17];

  char* ws = (char*)d_ws;
  float*          MASKF = (float*)(ws + 256);                 // 32 KB
  float*          BIASC = (float*)(ws + 40960);               // 12 KB concat bias
  __hip_bfloat16* XB    = (__hip_bfloat16*)(ws + 65536);      // 16 MB
  __hip_bfloat16* WQT   = (__hip_bfloat16*)(ws + 16842752);   // 3 x 2 MB contig
  __hip_bfloat16* WKT   = (__hip_bfloat16*)(ws + 18939904);
  __hip_bfloat16* WVT   = (__hip_bfloat16*)(ws + 21037056);
  __hip_bfloat16* WOT   = (__hip_bfloat16*)(ws + 23134208);
  __hip_bfloat16* W1T   = (__hip_bfloat16*)(ws + 25231360);   // 8 MB
  __hip_bfloat16* W2T   = (__hip_bfloat16*)(ws + 33619968);   // 8 MB
  __hip_bfloat16* QB    = (__hip_bfloat16*)(ws + 42008576);   // 3 x 16 MB contig
  __hip_bfloat16* KB    = (__hip_bfloat16*)(ws + 58785792);
  __hip_bfloat16* VB    = (__hip_bfloat16*)(ws + 75563008);
  __hip_bfloat16* OB    = (__hip_bfloat16*)(ws + 92340224);
  __hip_bfloat16* HB    = QB;  // FF hidden [8192][4096] reuses QKV+O (64 MB)
  __hip_bfloat16* VT    = (__hip_bfloat16*)(ws + 109117440);  // 16 MB
  __hip_bfloat16* OP    = VT;  // O-proj bf16 output reuses VT (fallback path)
  float*          R1    = (float*)(ws + 125894656);           // 32 MB f32 resid
  __hip_bfloat16* P0    = (__hip_bfloat16*)(ws + 159449088);  // 16 MB splitK bf16
  __hip_bfloat16* P1    = (__hip_bfloat16*)(ws + 176226304);  // 16 MB splitK bf16
  float*          OUT   = (float*)d_out;
  const bool use_splitk = ws_size >= 193003520ull;

  // fused prep + all 6 weight transposes in ONE launch
  prep_and_transpose<<<20512, 256, 0, stream>>>(
      (const float4*)x, (ushort4*)XB, (const unsigned int*)msk, MASKF,
      bq, bk, bv, BIASC, wq, wk, wv, wo, w1, w2,
      WQT, WKT, WVT, WOT, W1T, W2T);

  // fused QKV: A[8192,1024] x WQKVT[3072,1024]^T -> Q/K/V slabs (8-phase)
  gemm8<3><<<dim3((M_ / 256) * (3 * D_ / 256)), 512, 0, stream>>>(
      XB, WQT, BIASC, QB, M_, 3 * D_, D_, D_, D_);

  transpose_v<<<dim3(L_ / 32, D_ / 32, B_), dim3(32, 8), 0, stream>>>(VB, VT);
  attn_kernel<<<dim3(B_ * H_ * (L_ / 256)), 512, 0, stream>>>(QB, KB, VT, MASKF, OB);

  if (use_splitk) {
    // O-proj split-K=2 (256 wgs) -> bf16 partials; LN1 fused combine
    gemm8<4><<<dim3((M_ / 256) * (D_ / 256) * 2), 512, 0, stream>>>(
        OB, WOT, nullptr, P0, M_, D_, D_ / 2, D_, D_);
    ln_addres_sk<<<M_, 256, 0, stream>>>(P0, P1, x, bo, g1, be1, R1, XB);
  } else {
    gemm_bt<0><<<dim3(M_ / 128, D_ / 128), 256, 0, stream>>>(OB, WOT, bo, nullptr, OP, M_, D_, D_);
    ln_addres<<<M_, 256, 0, stream>>>(OP, x, g1, be1, R1, XB);
  }

  // FF1 (8-phase, relu)
  gemm8<1><<<dim3((M_ / 256) * (DFF_ / 256)), 512, 0, stream>>>(
      XB, W1T, b1, HB, M_, DFF_, D_, D_, D_);
  if (use_splitk) {
    // FF2 split-K=2: 256 wgs, bf16 partials -> P0/P1; fused combine + LN2
    gemm8<4><<<dim3((M_ / 256) * (D_ / 256) * 2), 512, 0, stream>>>(
        HB, W2T, nullptr, P0, M_, D_, DFF_ / 2, DFF_, DFF_);
    combine_ln2<<<M_, 256, 0, stream>>>(P0, P1, R1, b2, g2, be2, OUT);
  } else {
    gemm_bt<2><<<dim3(M_ / 128, D_ / 128), 256, 0, stream>>>(HB, W2T, b2, R1, OUT, M_, D_, DFF_);
    layernorm_kernel<<<M_, 256, 0, stream>>>(OUT, g2, be2, OUT, nullptr);
  }
}

// Round 18
// 410.192 us; speedup vs baseline: 1.0238x; 1.0238x over previous
//
#include <hip/hip_runtime.h>
#include <hip/hip_bf16.h>

#define B_   4
#define L_   2048
#define D_   1024
#define H_   16
#define DH_  64
#define DFF_ 4096
#define M_   (B_ * L_)   // 8192

typedef __attribute__((ext_vector_type(8))) short bf16x8;
typedef __attribute__((ext_vector_type(4))) float f32x4;

#define GLOAD16(gp, lp)                                                       \
  __builtin_amdgcn_global_load_lds(                                           \
      (const __attribute__((address_space(1))) unsigned int*)(gp),            \
      (__attribute__((address_space(3))) unsigned int*)(lp), 16, 0, 0)

#if __has_builtin(__builtin_amdgcn_exp2f)
#define EXP2F(x) __builtin_amdgcn_exp2f(x)
#else
#define EXP2F(x) exp2f(x)
#endif

__device__ __forceinline__ float bf2f(unsigned short u) {
  return __uint_as_float(((unsigned)u) << 16);
}

// ---- fused prep + weight transpose, single launch (20512 blocks) ---------
__global__ void prep_and_transpose(
    const float4* __restrict__ x4, ushort4* __restrict__ xb4,
    const unsigned int* __restrict__ mraw, float* __restrict__ maskf,
    const float* __restrict__ bq, const float* __restrict__ bk,
    const float* __restrict__ bv, float* __restrict__ biasc,
    const float* __restrict__ wq, const float* __restrict__ wk,
    const float* __restrict__ wv, const float* __restrict__ wo,
    const float* __restrict__ w1, const float* __restrict__ w2,
    __hip_bfloat16* __restrict__ WQT, __hip_bfloat16* __restrict__ WKT,
    __hip_bfloat16* __restrict__ WVT, __hip_bfloat16* __restrict__ WOT,
    __hip_bfloat16* __restrict__ W1T, __hip_bfloat16* __restrict__ W2T) {
  const int id = blockIdx.x;
  if (id < 8192) {
    const int i = id * 256 + threadIdx.x;
    float4 v = x4[i];
    __hip_bfloat16 a = __float2bfloat16(v.x);
    __hip_bfloat16 b = __float2bfloat16(v.y);
    __hip_bfloat16 c = __float2bfloat16(v.z);
    __hip_bfloat16 d = __float2bfloat16(v.w);
    ushort4 o;
    o.x = *reinterpret_cast<unsigned short*>(&a);
    o.y = *reinterpret_cast<unsigned short*>(&b);
    o.z = *reinterpret_cast<unsigned short*>(&c);
    o.w = *reinterpret_cast<unsigned short*>(&d);
    xb4[i] = o;
    return;
  }
  if (id < 8224) {
    __shared__ int flags[2];
    if (threadIdx.x < 2) flags[threadIdx.x] = 0;
    __syncthreads();
    int nf32 = 0, n01 = 0;
    for (int i = threadIdx.x; i < 2048; i += 256) {
      unsigned w = mraw[i];
      if (w != 0u && w != 0x3f800000u) nf32 = 1;
      if (w > 1u) n01 = 1;
    }
    if (nf32) atomicOr(&flags[0], 1);
    if (n01)  atomicOr(&flags[1], 1);
    __syncthreads();
    const int mode = (!flags[0]) ? 0 : ((!flags[1]) ? 1 : 2);  // f32/i32/u8
    const int mi = (id - 8192) * 256 + threadIdx.x;
    if (mi < B_ * L_) {
      bool mk;
      if (mode == 0)      mk = reinterpret_cast<const float*>(mraw)[mi] != 0.f;
      else if (mode == 1) mk = reinterpret_cast<const int*>(mraw)[mi] != 0;
      else                mk = reinterpret_cast<const unsigned char*>(mraw)[mi] != 0;
      // fixed-max softmax: keep -> -32 (fixed max folded), masked -> -1e12
      maskf[mi] = mk ? -1e12f : -32.0f;
    }
    if (id == 8192) {
#pragma unroll
      for (int j = 0; j < 4; ++j) {
        const int c = j * 256 + threadIdx.x;
        biasc[c] = bq[c];
        biasc[D_ + c] = bk[c];
        biasc[2 * D_ + c] = bv[c];
      }
    }
    return;
  }
  // ---- weight transpose tiles ----
  __shared__ float t[32][33];
  const int wid = id - 8224;
  const float* W;
  __hip_bfloat16* Wt;
  int K, N, rem;
  if (wid < 4096) {
    const int which = wid >> 10;
    W  = which == 0 ? wq : which == 1 ? wk : which == 2 ? wv : wo;
    Wt = which == 0 ? WQT : which == 1 ? WKT : which == 2 ? WVT : WOT;
    K = D_; N = D_; rem = wid & 1023;
  } else if (wid < 8192) {
    W = w1; Wt = W1T; K = D_; N = DFF_; rem = wid - 4096;
  } else {
    W = w2; Wt = W2T; K = DFF_; N = D_; rem = wid - 8192;
  }
  const int ntx = N >> 5;
  const int n0 = (rem % ntx) * 32, k0 = (rem / ntx) * 32;
  const int tx = threadIdx.x & 31, ty = threadIdx.x >> 5;  // 32x8 flattened
#pragma unroll
  for (int i = 0; i < 4; ++i)
    t[ty + i * 8][tx] = W[(size_t)(k0 + ty + i * 8) * N + n0 + tx];
  __syncthreads();
#pragma unroll
  for (int i = 0; i < 4; ++i)
    Wt[(size_t)(n0 + ty + i * 8) * K + k0 + tx] =
        __float2bfloat16(t[tx][ty + i * 8]);
}

// ---------------- V[b*L+l][D] bf16 -> VT[(b*D+d)][L] bf16 ----------------
__global__ void transpose_v(const __hip_bfloat16* __restrict__ Vin,
                            __hip_bfloat16* __restrict__ Vt) {
  __shared__ __hip_bfloat16 t[32][33];
  const int l0 = blockIdx.x * 32, d0 = blockIdx.y * 32, b = blockIdx.z;
  const int tx = threadIdx.x, ty = threadIdx.y;
#pragma unroll
  for (int i = 0; i < 4; ++i)
    t[ty + i * 8][tx] = Vin[(size_t)(b * L_ + l0 + ty + i * 8) * D_ + d0 + tx];
  __syncthreads();
#pragma unroll
  for (int i = 0; i < 4; ++i) {
    int d = d0 + ty + i * 8;
    Vt[(size_t)(b * D_ + d) * L_ + l0 + tx] = t[tx][ty + i * 8];
  }
}

// =================== 256x256 8-phase GEMM (T2+T3+T4+T5) ===================
#define STAGE8(matptr, stride, ldsbase, tile, kh, rowbase)                    \
  {                                                                           \
    _Pragma("unroll")                                                         \
    for (int j_ = 0; j_ < 2; ++j_) {                                          \
      const int s_ = j_ * 512 + tid;                                          \
      const int row_ = s_ >> 2;                                               \
      const int q_ = (s_ & 3) ^ ((row_ >> 1) & 3);                            \
      GLOAD16(&matptr[(size_t)((rowbase) + row_) * (stride) + (tile) * 64 +   \
                      (kh) * 32 + q_ * 8],                                    \
              (ldsbase) + (j_ * 512 + (w << 6)) * 16);                        \
    }                                                                         \
  }

#define PHASE8(bufoff, rh, ks, dovm, ...)                                     \
  {                                                                           \
    if ((rh) == 0) {                                                          \
      _Pragma("unroll")                                                       \
      for (int j = 0; j < 4; ++j) {                                           \
        const int br = wn * 64 + j * 16 + r16;                                \
        bfr[j] = *reinterpret_cast<const bf16x8*>(                            \
            ldsB + (bufoff) + (ks) * 16384 + br * 64 +                        \
            ((hi * 16) ^ (((br >> 1) & 3) << 4)));                            \
      }                                                                       \
    }                                                                         \
    bf16x8 af[4];                                                             \
    _Pragma("unroll")                                                         \
    for (int i = 0; i < 4; ++i) {                                             \
      const int ar = wm * 128 + (rh) * 64 + i * 16 + r16;                     \
      af[i] = *reinterpret_cast<const bf16x8*>(                               \
          ldsA + (bufoff) + (ks) * 16384 + ar * 64 +                          \
          ((hi * 16) ^ (((ar >> 1) & 3) << 4)));                              \
    }                                                                         \
    __VA_ARGS__;                                                              \
    __builtin_amdgcn_s_barrier();                                             \
    asm volatile("s_waitcnt lgkmcnt(0)" ::: "memory");                        \
    __builtin_amdgcn_sched_barrier(0);                                        \
    __builtin_amdgcn_s_setprio(1);                                            \
    _Pragma("unroll")                                                         \
    for (int i = 0; i < 4; ++i)                                               \
      _Pragma("unroll")                                                       \
      for (int j = 0; j < 4; ++j)                                             \
        acc[(rh) * 4 + i][j] = __builtin_amdgcn_mfma_f32_16x16x32_bf16(       \
            af[i], bfr[j], acc[(rh) * 4 + i][j], 0, 0, 0);                    \
    __builtin_amdgcn_s_setprio(0);                                            \
    if (dovm) {                                                               \
      asm volatile("s_waitcnt vmcnt(4)" ::: "memory");                        \
      __builtin_amdgcn_sched_barrier(0);                                      \
    }                                                                         \
    __builtin_amdgcn_s_barrier();                                             \
  }

template <int EP>
__global__ __launch_bounds__(512, 1) void gemm8(
    const __hip_bfloat16* __restrict__ A, const __hip_bfloat16* __restrict__ Bt,
    const float* __restrict__ bias, void* __restrict__ out,
    int M, int N, int K, int lda, int ldb) {
  __shared__ __align__(16) char lds8[131072];
  char* const ldsA = lds8;
  char* const ldsB = lds8 + 65536;

  const int tid = threadIdx.x;
  const int lane = tid & 63;
  const int w = tid >> 6;           // 0..7
  const int wm = w >> 2;            // 0..1
  const int wn = w & 3;             // 0..3
  const int r16 = lane & 15;
  const int hi = lane >> 4;

  const int nwg = gridDim.x;
  const int orig = blockIdx.x;
  const int swz = (orig & 7) * (nwg >> 3) + (orig >> 3);

  int bm, bn, kh = 0;
  const __hip_bfloat16* Ap = A;
  const __hip_bfloat16* Bp = Bt;
  if (EP == 4) {
    kh = swz & 1;
    const int rest = swz >> 1;
    bm = (rest & 31) * 256;
    bn = (rest >> 5) * 256;
    Ap += (size_t)kh * K;
    Bp += (size_t)kh * K;
  } else {
    bm = (swz & 31) * 256;          // M/256 == 32 always here
    bn = (swz >> 5) * 256;
  }

  f32x4 acc[8][4];
#pragma unroll
  for (int i = 0; i < 8; ++i)
#pragma unroll
    for (int j = 0; j < 4; ++j) acc[i][j] = (f32x4){0.f, 0.f, 0.f, 0.f};
  bf16x8 bfr[4];

  const int nkt = K >> 6;           // K-tiles of 64
  const int nit = nkt >> 1;         // iterations (2 K-tiles each)

  // prologue: t0 {kh0,kh1}, t1 {kh0}
  STAGE8(Ap, lda, ldsA, 0, 0, bm);
  STAGE8(Bp, ldb, ldsB, 0, 0, bn);
  STAGE8(Ap, lda, ldsA + 16384, 0, 1, bm);
  STAGE8(Bp, ldb, ldsB + 16384, 0, 1, bn);
  STAGE8(Ap, lda, ldsA + 32768, 1, 0, bm);
  STAGE8(Bp, ldb, ldsB + 32768, 1, 0, bn);
  asm volatile("s_waitcnt vmcnt(4)" ::: "memory");
  __builtin_amdgcn_sched_barrier(0);
  __builtin_amdgcn_s_barrier();

  for (int it = 0; it < nit; ++it) {
    const int kt = it * 2;
    const bool hn = (it + 1) < nit;
    // tile kt from buf0
    PHASE8(0, 0, 0, 0, STAGE8(Ap, lda, ldsA + 49152, kt + 1, 1, bm));
    PHASE8(0, 1, 0, 0, STAGE8(Bp, ldb, ldsB + 49152, kt + 1, 1, bn));
    PHASE8(0, 0, 1, 0, if (hn) STAGE8(Ap, lda, ldsA, kt + 2, 0, bm));
    PHASE8(0, 1, 1, 1, if (hn) STAGE8(Bp, ldb, ldsB, kt + 2, 0, bn));
    // tile kt+1 from buf1
    PHASE8(32768, 0, 0, 0, if (hn) STAGE8(Ap, lda, ldsA + 16384, kt + 2, 1, bm));
    PHASE8(32768, 1, 0, 0, if (hn) STAGE8(Bp, ldb, ldsB + 16384, kt + 2, 1, bn));
    PHASE8(32768, 0, 1, 0, if (hn) STAGE8(Ap, lda, ldsA + 32768, kt + 3, 0, bm));
    PHASE8(32768, 1, 1, 1, if (hn) STAGE8(Bp, ldb, ldsB + 32768, kt + 3, 0, bn));
  }

  // epilogue
#pragma unroll
  for (int ri = 0; ri < 8; ++ri) {
#pragma unroll
    for (int j = 0; j < 4; ++j) {
      const int col = bn + wn * 64 + j * 16 + r16;
      const float bv = (EP == 4) ? 0.f : bias[col];
#pragma unroll
      for (int r = 0; r < 4; ++r) {
        const int row = bm + wm * 128 + ri * 16 + hi * 4 + r;
        const float v = acc[ri][j][r] + bv;
        if (EP == 1) {
          ((__hip_bfloat16*)out)[(size_t)row * N + col] =
              __float2bfloat16(v > 0.f ? v : 0.f);
        } else if (EP == 3) {  // QKV routing
          __hip_bfloat16* outp =
              (__hip_bfloat16*)out + (size_t)(col >> 10) * (M_ * D_);
          outp[(size_t)row * 1024 + (col & 1023)] = __float2bfloat16(v);
        } else {  // EP == 4: split-K partial, bf16
          __hip_bfloat16* outp =
              (__hip_bfloat16*)out + (size_t)kh * ((size_t)M * N);
          outp[(size_t)row * N + col] = __float2bfloat16(v);
        }
      }
    }
  }
}

// ---------------- GEMM 128x128 2-phase (fallback path only) ---------------
template <int EP>
__global__ __launch_bounds__(256) void gemm_bt(
    const __hip_bfloat16* __restrict__ A, const __hip_bfloat16* __restrict__ Bt,
    const float* __restrict__ bias, const float* __restrict__ res,
    void* __restrict__ out, int M, int N, int K) {
  __shared__ __align__(16) char As[128 * 64];
  __shared__ __align__(16) char Bs[128 * 64];
  const int tid = threadIdx.x;
  const int lane = tid & 63;
  const int w = tid >> 6;
  const int wm = w >> 1, wn = w & 1;
  const int bm = blockIdx.x * 128;
  const int bn = blockIdx.y * 128;
  const int r16 = lane & 15;
  const int hi = lane >> 4;

  f32x4 acc[4][4];
#pragma unroll
  for (int m = 0; m < 4; ++m)
#pragma unroll
    for (int n = 0; n < 4; ++n) acc[m][n] = (f32x4){0.f, 0.f, 0.f, 0.f};

  for (int k0 = 0; k0 < K; k0 += 32) {
    __syncthreads();
#pragma unroll
    for (int c = 0; c < 2; ++c) {
      const int seg = c * 256 + tid;
      const int row = seg >> 2;
      const int csl = (seg & 3) ^ (row & 3);
      GLOAD16(&A[(size_t)(bm + row) * K + k0 + csl * 8],
              As + (c * 256 + w * 64) * 16);
      GLOAD16(&Bt[(size_t)(bn + row) * K + k0 + csl * 8],
              Bs + (c * 256 + w * 64) * 16);
    }
    __syncthreads();

    bf16x8 af[4], bfr[4];
#pragma unroll
    for (int m = 0; m < 4; ++m) {
      const int arow = wm * 64 + m * 16 + r16;
      af[m] = *reinterpret_cast<const bf16x8*>(
          As + arow * 64 + ((hi * 16) ^ ((arow & 3) << 4)));
    }
#pragma unroll
    for (int n = 0; n < 4; ++n) {
      const int brow = wn * 64 + n * 16 + r16;
      bfr[n] = *reinterpret_cast<const bf16x8*>(
          Bs + brow * 64 + ((hi * 16) ^ ((brow & 3) << 4)));
    }
#pragma unroll
    for (int m = 0; m < 4; ++m)
#pragma unroll
      for (int n = 0; n < 4; ++n)
        acc[m][n] = __builtin_amdgcn_mfma_f32_16x16x32_bf16(af[m], bfr[n],
                                                            acc[m][n], 0, 0, 0);
  }

  const int rg = hi * 4;
#pragma unroll
  for (int m = 0; m < 4; ++m) {
#pragma unroll
    for (int n = 0; n < 4; ++n) {
      const int col = bn + wn * 64 + n * 16 + r16;
      const float bv = bias[col];
#pragma unroll
      for (int r = 0; r < 4; ++r) {
        const int row = bm + wm * 64 + m * 16 + rg + r;
        const size_t idx = (size_t)row * N + col;
        float v = acc[m][n][r] + bv;
        if (EP == 0) {
          ((__hip_bfloat16*)out)[idx] = __float2bfloat16(v);
        } else {
          ((float*)out)[idx] = v + res[idx];
        }
      }
    }
  }
}

// ----- flash attention (best measured: staged K/V, fixed-max, MFMA den) ---
// grid 1024 blocks (XCD-remapped); block 256 = 4 waves; wave owns 32 q rows.
__global__ __launch_bounds__(256) void attn_kernel(
    const __hip_bfloat16* __restrict__ Qg, const __hip_bfloat16* __restrict__ Kg,
    const __hip_bfloat16* __restrict__ VTg,  // [(b*D + h*64+dh)][L]
    const float* __restrict__ maskf,         // [B*L]: -32 keep / -1e12 masked
    __hip_bfloat16* __restrict__ Og) {
  __shared__ __align__(16) char Kl[64 * 128];        // [kv][d], swizzled
  __shared__ __align__(16) char Vl[64 * 128];        // [dh][kv], swizzled
  __shared__ __align__(16) char Pl[4][32 * 128];     // per-wave [q][k], XOR swz
  __shared__ float maskb[64];

  const int tid = threadIdx.x;
  const int lane = tid & 63;
  const int w = tid >> 6;
  const int hi = lane >> 4;
  const int r16 = lane & 15;
  const int swzk = (r16 & 7) << 4;

  const int nwg = gridDim.x;            // 1024
  const int orig = blockIdx.x;
  const int swb = (orig & 7) * (nwg >> 3) + (orig >> 3);
  const int qb = swb & 15;
  const int bh = swb >> 4;
  const int b = bh >> 4;
  const int h = bh & 15;
  const int qbase = qb * 128 + w * 32;

  const float C = 0.18033688011112042f;  // 0.125 * log2(e)
  const short ob = (short)0x3f80;        // bf16 1.0
  const bf16x8 vone = {ob, ob, ob, ob, ob, ob, ob, ob};

  bf16x8 qf[2][2];
#pragma unroll
  for (int m = 0; m < 2; ++m)
#pragma unroll
    for (int ks = 0; ks < 2; ++ks)
      qf[m][ks] = *reinterpret_cast<const bf16x8*>(
          &Qg[(size_t)(b * L_ + qbase + m * 16 + r16) * D_ + h * DH_ +
              ks * 32 + hi * 8]);

  f32x4 o[2][4];
  f32x4 oden[2];
#pragma unroll
  for (int m = 0; m < 2; ++m) {
    oden[m] = (f32x4){0.f, 0.f, 0.f, 0.f};
#pragma unroll
    for (int nd = 0; nd < 4; ++nd) o[m][nd] = (f32x4){0.f, 0.f, 0.f, 0.f};
  }

  char* const Plw = Pl[w];

  for (int kv0 = 0; kv0 < L_; kv0 += 64) {
    __syncthreads();
#pragma unroll
    for (int c = 0; c < 2; ++c) {
      const int seg = c * 256 + tid;
      const int row = seg >> 3;                 // 0..63
      const int csl = (seg & 7) ^ (row & 7);
      GLOAD16(&Kg[(size_t)(b * L_ + kv0 + row) * D_ + h * DH_ + csl * 8],
              Kl + (c * 256 + w * 64) * 16);
      GLOAD16(&VTg[(size_t)(b * D_ + h * DH_ + row) * L_ + kv0 + csl * 8],
              Vl + (c * 256 + w * 64) * 16);
    }
    if (tid < 64) maskb[tid] = maskf[(size_t)b * L_ + kv0 + tid];
    __syncthreads();

    // S^T tiles: lane q = m*16+r16, k = n*16+hi*4+r
    f32x4 sacc[2][4];
#pragma unroll
    for (int m = 0; m < 2; ++m)
#pragma unroll
      for (int n = 0; n < 4; ++n) sacc[m][n] = (f32x4){0.f, 0.f, 0.f, 0.f};
    __builtin_amdgcn_s_setprio(1);
#pragma unroll
    for (int n = 0; n < 4; ++n) {
      const int krow = n * 16 + r16;
#pragma unroll
      for (int ks = 0; ks < 2; ++ks) {
        const bf16x8 kf = *reinterpret_cast<const bf16x8*>(
            Kl + krow * 128 + ((ks * 64 + hi * 16) ^ swzk));
#pragma unroll
        for (int m = 0; m < 2; ++m)
          sacc[m][n] = __builtin_amdgcn_mfma_f32_16x16x32_bf16(
              kf, qf[m][ks], sacc[m][n], 0, 0, 0);
      }
    }
    __builtin_amdgcn_s_setprio(0);

    // fixed-max softmax: e = 2^(S*C + mask); no max tracking, no sum chain.
    float4 mv[4];
#pragma unroll
    for (int n = 0; n < 4; ++n)
      mv[n] = *reinterpret_cast<const float4*>(&maskb[n * 16 + hi * 4]);
#pragma unroll
    for (int m = 0; m < 2; ++m) {
      const int prow = m * 16 + r16;
#pragma unroll
      for (int n = 0; n < 4; ++n) {
        const float e0 = EXP2F(fmaf(sacc[m][n][0], C, mv[n].x));
        const float e1 = EXP2F(fmaf(sacc[m][n][1], C, mv[n].y));
        const float e2 = EXP2F(fmaf(sacc[m][n][2], C, mv[n].z));
        const float e3 = EXP2F(fmaf(sacc[m][n][3], C, mv[n].w));
        union { unsigned long long u; unsigned short us[4]; } pk;
        __hip_bfloat16 t0 = __float2bfloat16(e0);
        __hip_bfloat16 t1 = __float2bfloat16(e1);
        __hip_bfloat16 t2 = __float2bfloat16(e2);
        __hip_bfloat16 t3 = __float2bfloat16(e3);
        pk.us[0] = *reinterpret_cast<unsigned short*>(&t0);
        pk.us[1] = *reinterpret_cast<unsigned short*>(&t1);
        pk.us[2] = *reinterpret_cast<unsigned short*>(&t2);
        pk.us[3] = *reinterpret_cast<unsigned short*>(&t3);
        *reinterpret_cast<unsigned long long*>(
            Plw + prow * 128 + ((n * 32 + hi * 8) ^ swzk)) = pk.u;
      }
    }

    // O += P V ; oden += P * ones (denominator rides the matrix pipe)
    bf16x8 pa[2][2];
#pragma unroll
    for (int m = 0; m < 2; ++m)
#pragma unroll
      for (int ks = 0; ks < 2; ++ks)
        pa[m][ks] = *reinterpret_cast<const bf16x8*>(
            Plw + (m * 16 + r16) * 128 + ((ks * 64 + hi * 16) ^ swzk));
    __builtin_amdgcn_s_setprio(1);
#pragma unroll
    for (int m = 0; m < 2; ++m)
#pragma unroll
      for (int ks = 0; ks < 2; ++ks)
        oden[m] = __builtin_amdgcn_mfma_f32_16x16x32_bf16(pa[m][ks], vone,
                                                          oden[m], 0, 0, 0);
#pragma unroll
    for (int nd = 0; nd < 4; ++nd) {
      const int vrow = nd * 16 + r16;
#pragma unroll
      for (int ks = 0; ks < 2; ++ks) {
        const bf16x8 vb = *reinterpret_cast<const bf16x8*>(
            Vl + vrow * 128 + ((ks * 64 + hi * 16) ^ swzk));
#pragma unroll
        for (int m = 0; m < 2; ++m)
          o[m][nd] = __builtin_amdgcn_mfma_f32_16x16x32_bf16(pa[m][ks], vb,
                                                             o[m][nd], 0, 0, 0);
      }
    }
    __builtin_amdgcn_s_setprio(0);
  }

  // normalize + store: oden row-layout == o row-layout (row = hi*4+r)
#pragma unroll
  for (int m = 0; m < 2; ++m) {
#pragma unroll
    for (int r = 0; r < 4; ++r) {
      const float ir = 1.f / oden[m][r];
      const int q = qbase + m * 16 + hi * 4 + r;
#pragma unroll
      for (int nd = 0; nd < 4; ++nd)
        Og[(size_t)(b * L_ + q) * D_ + h * DH_ + nd * 16 + r16] =
            __float2bfloat16(o[m][nd][r] * ir);
    }
  }
}

// ---------------- LayerNorm (row=1024) plain (fallback path) --------------
__global__ __launch_bounds__(256) void layernorm_kernel(
    const float* __restrict__ in, const float* __restrict__ g,
    const float* __restrict__ be, float* __restrict__ outf,
    __hip_bfloat16* __restrict__ outb) {
  const int row = blockIdx.x;
  const int tid = threadIdx.x;
  const float4 v = reinterpret_cast<const float4*>(in + (size_t)row * D_)[tid];
  float s = v.x + v.y + v.z + v.w;
  float ss = v.x * v.x + v.y * v.y + v.z * v.z + v.w * v.w;
#pragma unroll
  for (int off = 1; off < 64; off <<= 1) {
    s += __shfl_xor(s, off, 64);
    ss += __shfl_xor(ss, off, 64);
  }
  __shared__ float red[8];
  const int w = tid >> 6, lane = tid & 63;
  if (lane == 0) { red[w] = s; red[4 + w] = ss; }
  __syncthreads();
  s = red[0] + red[1] + red[2] + red[3];
  ss = red[4] + red[5] + red[6] + red[7];
  const float mu = s * (1.f / D_);
  const float rs = rsqrtf(ss * (1.f / D_) - mu * mu + 1e-5f);
  const float4 gv = reinterpret_cast<const float4*>(g)[tid];
  const float4 bv = reinterpret_cast<const float4*>(be)[tid];
  float4 ov;
  ov.x = (v.x - mu) * rs * gv.x + bv.x;
  ov.y = (v.y - mu) * rs * gv.y + bv.y;
  ov.z = (v.z - mu) * rs * gv.z + bv.z;
  ov.w = (v.w - mu) * rs * gv.w + bv.w;
  reinterpret_cast<float4*>(outf + (size_t)row * D_)[tid] = ov;
  if (outb) {
    __hip_bfloat16 t[4] = {__float2bfloat16(ov.x), __float2bfloat16(ov.y),
                           __float2bfloat16(ov.z), __float2bfloat16(ov.w)};
    *reinterpret_cast<uint2*>(&outb[(size_t)row * D_ + tid * 4]) =
        *reinterpret_cast<const uint2*>(t);
  }
}

// -------- LN1 fused: v = OP(bf16) + x; LN -> R1(f32), XB(bf16) (fallback) --
__global__ __launch_bounds__(256) void ln_addres(
    const __hip_bfloat16* __restrict__ OP, const float* __restrict__ x,
    const float* __restrict__ g, const float* __restrict__ be,
    float* __restrict__ outf, __hip_bfloat16* __restrict__ outb) {
  const int row = blockIdx.x;
  const int tid = threadIdx.x;
  const ushort4 a4 = reinterpret_cast<const ushort4*>(OP + (size_t)row * D_)[tid];
  const float4 xr = reinterpret_cast<const float4*>(x + (size_t)row * D_)[tid];
  float4 v;
  v.x = bf2f(a4.x) + xr.x;
  v.y = bf2f(a4.y) + xr.y;
  v.z = bf2f(a4.z) + xr.z;
  v.w = bf2f(a4.w) + xr.w;
  float s = v.x + v.y + v.z + v.w;
  float ss = v.x * v.x + v.y * v.y + v.z * v.z + v.w * v.w;
#pragma unroll
  for (int off = 1; off < 64; off <<= 1) {
    s += __shfl_xor(s, off, 64);
    ss += __shfl_xor(ss, off, 64);
  }
  __shared__ float red[8];
  const int w = tid >> 6, lane = tid & 63;
  if (lane == 0) { red[w] = s; red[4 + w] = ss; }
  __syncthreads();
  s = red[0] + red[1] + red[2] + red[3];
  ss = red[4] + red[5] + red[6] + red[7];
  const float mu = s * (1.f / D_);
  const float rs = rsqrtf(ss * (1.f / D_) - mu * mu + 1e-5f);
  const float4 gv = reinterpret_cast<const float4*>(g)[tid];
  const float4 bv = reinterpret_cast<const float4*>(be)[tid];
  float4 ov;
  ov.x = (v.x - mu) * rs * gv.x + bv.x;
  ov.y = (v.y - mu) * rs * gv.y + bv.y;
  ov.z = (v.z - mu) * rs * gv.z + bv.z;
  ov.w = (v.w - mu) * rs * gv.w + bv.w;
  reinterpret_cast<float4*>(outf + (size_t)row * D_)[tid] = ov;
  __hip_bfloat16 t[4] = {__float2bfloat16(ov.x), __float2bfloat16(ov.y),
                         __float2bfloat16(ov.z), __float2bfloat16(ov.w)};
  *reinterpret_cast<uint2*>(&outb[(size_t)row * D_ + tid * 4]) =
      *reinterpret_cast<const uint2*>(t);
}

// -------- LN1 fused with O-proj split-K combine: v = P0+P1+x+bo; LN -------
// residual out in f32 (precision-critical for final LN2)
__global__ __launch_bounds__(256) void ln_addres_sk(
    const __hip_bfloat16* __restrict__ P0, const __hip_bfloat16* __restrict__ P1,
    const float* __restrict__ x, const float* __restrict__ bo,
    const float* __restrict__ g, const float* __restrict__ be,
    float* __restrict__ outf, __hip_bfloat16* __restrict__ outb) {
  const int row = blockIdx.x;
  const int tid = threadIdx.x;
  const ushort4 a4 = reinterpret_cast<const ushort4*>(P0 + (size_t)row * D_)[tid];
  const ushort4 b4 = reinterpret_cast<const ushort4*>(P1 + (size_t)row * D_)[tid];
  const float4 xr = reinterpret_cast<const float4*>(x + (size_t)row * D_)[tid];
  const float4 bb = reinterpret_cast<const float4*>(bo)[tid];
  float4 v;
  v.x = bf2f(a4.x) + bf2f(b4.x) + xr.x + bb.x;
  v.y = bf2f(a4.y) + bf2f(b4.y) + xr.y + bb.y;
  v.z = bf2f(a4.z) + bf2f(b4.z) + xr.z + bb.z;
  v.w = bf2f(a4.w) + bf2f(b4.w) + xr.w + bb.w;
  float s = v.x + v.y + v.z + v.w;
  float ss = v.x * v.x + v.y * v.y + v.z * v.z + v.w * v.w;
#pragma unroll
  for (int off = 1; off < 64; off <<= 1) {
    s += __shfl_xor(s, off, 64);
    ss += __shfl_xor(ss, off, 64);
  }
  __shared__ float red[8];
  const int w = tid >> 6, lane = tid & 63;
  if (lane == 0) { red[w] = s; red[4 + w] = ss; }
  __syncthreads();
  s = red[0] + red[1] + red[2] + red[3];
  ss = red[4] + red[5] + red[6] + red[7];
  const float mu = s * (1.f / D_);
  const float rs = rsqrtf(ss * (1.f / D_) - mu * mu + 1e-5f);
  const float4 gv = reinterpret_cast<const float4*>(g)[tid];
  const float4 bv = reinterpret_cast<const float4*>(be)[tid];
  float4 ov;
  ov.x = (v.x - mu) * rs * gv.x + bv.x;
  ov.y = (v.y - mu) * rs * gv.y + bv.y;
  ov.z = (v.z - mu) * rs * gv.z + bv.z;
  ov.w = (v.w - mu) * rs * gv.w + bv.w;
  reinterpret_cast<float4*>(outf + (size_t)row * D_)[tid] = ov;
  __hip_bfloat16 t[4] = {__float2bfloat16(ov.x), __float2bfloat16(ov.y),
                         __float2bfloat16(ov.z), __float2bfloat16(ov.w)};
  *reinterpret_cast<uint2*>(&outb[(size_t)row * D_ + tid * 4]) =
      *reinterpret_cast<const uint2*>(t);
}

// ------- combine bf16 split-K partials + f32 residual + bias + LN ---------
__global__ __launch_bounds__(256) void combine_ln2(
    const __hip_bfloat16* __restrict__ P0, const __hip_bfloat16* __restrict__ P1,
    const float* __restrict__ res, const float* __restrict__ b2,
    const float* __restrict__ g, const float* __restrict__ be,
    float* __restrict__ out) {
  const int row = blockIdx.x;
  const int tid = threadIdx.x;
  const ushort4 a4 =
      reinterpret_cast<const ushort4*>(P0 + (size_t)row * D_)[tid];
  const ushort4 b4 =
      reinterpret_cast<const ushort4*>(P1 + (size_t)row * D_)[tid];
  const float4 rr = reinterpret_cast<const float4*>(res + (size_t)row * D_)[tid];
  const float4 bb = reinterpret_cast<const float4*>(b2)[tid];
  float4 v;
  v.x = bf2f(a4.x) + bf2f(b4.x) + rr.x + bb.x;
  v.y = bf2f(a4.y) + bf2f(b4.y) + rr.y + bb.y;
  v.z = bf2f(a4.z) + bf2f(b4.z) + rr.z + bb.z;
  v.w = bf2f(a4.w) + bf2f(b4.w) + rr.w + bb.w;
  float s = v.x + v.y + v.z + v.w;
  float ss = v.x * v.x + v.y * v.y + v.z * v.z + v.w * v.w;
#pragma unroll
  for (int off = 1; off < 64; off <<= 1) {
    s += __shfl_xor(s, off, 64);
    ss += __shfl_xor(ss, off, 64);
  }
  __shared__ float red[8];
  const int w = tid >> 6, lane = tid & 63;
  if (lane == 0) { red[w] = s; red[4 + w] = ss; }
  __syncthreads();
  s = red[0] + red[1] + red[2] + red[3];
  ss = red[4] + red[5] + red[6] + red[7];
  const float mu = s * (1.f / D_);
  const float rs = rsqrtf(ss * (1.f / D_) - mu * mu + 1e-5f);
  const float4 gv = reinterpret_cast<const float4*>(g)[tid];
  const float4 bv = reinterpret_cast<const float4*>(be)[tid];
  float4 ov;
  ov.x = (v.x - mu) * rs * gv.x + bv.x;
  ov.y = (v.y - mu) * rs * gv.y + bv.y;
  ov.z = (v.z - mu) * rs * gv.z + bv.z;
  ov.w = (v.w - mu) * rs * gv.w + bv.w;
  reinterpret_cast<float4*>(out + (size_t)row * D_)[tid] = ov;
}

// ---------------- launch ----------------
extern "C" void kernel_launch(void* const* d_in, const int* in_sizes, int n_in,
                              void* d_out, int out_size, void* d_ws,
                              size_t ws_size, hipStream_t stream) {
  (void)in_sizes; (void)n_in; (void)out_size;
  const float* x   = (const float*)d_in[0];
  const void*  msk = d_in[1];
  const float* wq  = (const float*)d_in[2];
  const float* bq  = (const float*)d_in[3];
  const float* wk  = (const float*)d_in[4];
  const float* bk  = (const float*)d_in[5];
  const float* wv  = (const float*)d_in[6];
  const float* bv  = (const float*)d_in[7];
  const float* wo  = (const float*)d_in[8];
  const float* bo  = (const float*)d_in[9];
  const float* w1  = (const float*)d_in[10];
  const float* b1  = (const float*)d_in[11];
  const float* w2  = (const float*)d_in[12];
  const float* b2  = (const float*)d_in[13];
  const float* g1  = (const float*)d_in[14];
  const float* be1 = (const float*)d_in[15];
  const float* g2  = (const float*)d_in[16];
  const float* be2 = (const float*)d_in[17];

  char* ws = (char*)d_ws;
  float*          MASKF = (float*)(ws + 256);                 // 32 KB
  float*          BIASC = (float*)(ws + 40960);               // 12 KB concat bias
  __hip_bfloat16* XB    = (__hip_bfloat16*)(ws + 65536);      // 16 MB
  __hip_bfloat16* WQT   = (__hip_bfloat16*)(ws + 16842752);   // 3 x 2 MB contig
  __hip_bfloat16* WKT   = (__hip_bfloat16*)(ws + 18939904);
  __hip_bfloat16* WVT   = (__hip_bfloat16*)(ws + 21037056);
  __hip_bfloat16* WOT   = (__hip_bfloat16*)(ws + 23134208);
  __hip_bfloat16* W1T   = (__hip_bfloat16*)(ws + 25231360);   // 8 MB
  __hip_bfloat16* W2T   = (__hip_bfloat16*)(ws + 33619968);   // 8 MB
  __hip_bfloat16* QB    = (__hip_bfloat16*)(ws + 42008576);   // 3 x 16 MB contig
  __hip_bfloat16* KB    = (__hip_bfloat16*)(ws + 58785792);
  __hip_bfloat16* VB    = (__hip_bfloat16*)(ws + 75563008);
  __hip_bfloat16* OB    = (__hip_bfloat16*)(ws + 92340224);
  __hip_bfloat16* HB    = QB;  // FF hidden [8192][4096] reuses QKV+O (64 MB)
  __hip_bfloat16* VT    = (__hip_bfloat16*)(ws + 109117440);  // 16 MB
  __hip_bfloat16* OP    = VT;  // O-proj bf16 output reuses VT (fallback path)
  float*          R1    = (float*)(ws + 125894656);           // 32 MB f32 resid
  __hip_bfloat16* P0    = (__hip_bfloat16*)(ws + 159449088);  // 16 MB splitK bf16
  __hip_bfloat16* P1    = (__hip_bfloat16*)(ws + 176226304);  // 16 MB splitK bf16
  float*          OUT   = (float*)d_out;
  const bool use_splitk = ws_size >= 193003520ull;

  // fused prep + all 6 weight transposes in ONE launch
  prep_and_transpose<<<20512, 256, 0, stream>>>(
      (const float4*)x, (ushort4*)XB, (const unsigned int*)msk, MASKF,
      bq, bk, bv, BIASC, wq, wk, wv, wo, w1, w2,
      WQT, WKT, WVT, WOT, W1T, W2T);

  // fused QKV: A[8192,1024] x WQKVT[3072,1024]^T -> Q/K/V slabs (8-phase)
  gemm8<3><<<dim3((M_ / 256) * (3 * D_ / 256)), 512, 0, stream>>>(
      XB, WQT, BIASC, QB, M_, 3 * D_, D_, D_, D_);

  transpose_v<<<dim3(L_ / 32, D_ / 32, B_), dim3(32, 8), 0, stream>>>(VB, VT);
  attn_kernel<<<dim3(B_ * H_ * (L_ / 128)), 256, 0, stream>>>(QB, KB, VT, MASKF, OB);

  if (use_splitk) {
    // O-proj split-K=2 (256 wgs) -> bf16 partials; LN1 fused combine
    gemm8<4><<<dim3((M_ / 256) * (D_ / 256) * 2), 512, 0, stream>>>(
        OB, WOT, nullptr, P0, M_, D_, D_ / 2, D_, D_);
    ln_addres_sk<<<M_, 256, 0, stream>>>(P0, P1, x, bo, g1, be1, R1, XB);
  } else {
    gemm_bt<0><<<dim3(M_ / 128, D_ / 128), 256, 0, stream>>>(OB, WOT, bo, nullptr, OP, M_, D_, D_);
    ln_addres<<<M_, 256, 0, stream>>>(OP, x, g1, be1, R1, XB);
  }

  // FF1 (8-phase, relu)
  gemm8<1><<<dim3((M_ / 256) * (DFF_ / 256)), 512, 0, stream>>>(
      XB, W1T, b1, HB, M_, DFF_, D_, D_, D_);
  if (use_splitk) {
    // FF2 split-K=2: 256 wgs, bf16 partials -> P0/P1; fused combine + LN2
    gemm8<4><<<dim3((M_ / 256) * (D_ / 256) * 2), 512, 0, stream>>>(
        HB, W2T, nullptr, P0, M_, D_, DFF_ / 2, DFF_, DFF_);
    combine_ln2<<<M_, 256, 0, stream>>>(P0, P1, R1, b2, g2, be2, OUT);
  } else {
    gemm_bt<2><<<dim3(M_ / 128, D_ / 128), 256, 0, stream>>>(HB, W2T, b2, R1, OUT, M_, D_, DFF_);
    layernorm_kernel<<<M_, 256, 0, stream>>>(OUT, g2, be2, OUT, nullptr);
  }
}